// Round 20
// baseline (1210.656 us; speedup 1.0000x reference)
//
#include <hip/hip_runtime.h>
#include <math.h>

typedef _Float16 f16;
typedef f16 f16x8 __attribute__((ext_vector_type(8)));
typedef float f32x4 __attribute__((ext_vector_type(4)));

#define NTOT 3840
#define KP   3968          // 3840 neurons + 128 inputs
#define BATCH 32
#define TSTEPS 100
#define NIN 128
#define NWG 241            // 240 col-tile WGs (16 cols, 512 thr) + 1 readout WG
#define RSTRIDE (BATCH*KP) // ushorts per r buffer (126,976)

__device__ __forceinline__ bool is_dend(int k){
  return (k>=512 && k<1536) || (k>=2432 && k<3456);
}
__device__ __forceinline__ bool is_inh(int k){
  return (k>=1536 && k<1920) || (k>=3456 && k<3840);
}
__device__ __forceinline__ ushort f2h(float v){ f16 h=(f16)v; return *(ushort*)&h; }
__device__ __forceinline__ float h2f(ushort u){ f16 h=*(f16*)&u; return (float)h; }

// ---------- one-time: WT[n][k] = fp16(w_eff^T), mask derived analytically ----------
__global__ __launch_bounds__(256) void k_prep_w(const float* __restrict__ w_rec,
    const float* __restrict__ w_in, ushort* __restrict__ WT){
  __shared__ ushort tile[64][72];
  const int bid = blockIdx.x;
  const int kt = bid / 60, nt = bid % 60;
  const int k0 = kt*64, n0 = nt*64;
  const int t = threadIdx.x;
  const int tr = t>>2, tq = t&3;
  const int k = k0 + tr;
  const int cbase = n0 + tq*16;
  if (k < NTOT){
    const float sgn = is_inh(k) ? -1.f : 1.f;
    const bool rowSr  = (k>=512  && k<1536);
    const bool rowPfc = (k>=2432 && k<3456);
    #pragma unroll
    for (int q=0;q<4;q++){
      float4 w = *(const float4*)(w_rec + (size_t)k*NTOT + cbase + q*4);
      float v[4] = {sgn*fabsf(w.x), sgn*fabsf(w.y), sgn*fabsf(w.z), sgn*fabsf(w.w)};
      #pragma unroll
      for (int e=0;e<4;e++){
        const int n = cbase + q*4 + e;
        if (n==k || (rowSr && n<512) || (rowPfc && n>=1920 && n<2432)) v[e]=0.f;
        tile[tr][tq*16+q*4+e] = f2h(v[e]);
      }
    }
  } else {
    const float* src = w_in + (size_t)(k-NTOT)*NTOT + cbase;
    #pragma unroll
    for (int q=0;q<4;q++){
      float4 w = *(const float4*)(src + q*4);
      tile[tr][tq*16+q*4+0] = f2h(w.x);
      tile[tr][tq*16+q*4+1] = f2h(w.y);
      tile[tr][tq*16+q*4+2] = f2h(w.z);
      tile[tr][tq*16+q*4+3] = f2h(w.w);
    }
  }
  __syncthreads();
  const int n  = n0 + tr;
  const int kq = tq*16;
  uint u[8];
  #pragma unroll
  for (int q=0;q<8;q++)
    u[q] = (uint)tile[kq+2*q][tr] | ((uint)tile[kq+2*q+1][tr] << 16);
  uint4* dst = (uint4*)(WT + (size_t)n*KP + k0 + kq);
  dst[0] = make_uint4(u[0],u[1],u[2],u[3]);
  dst[1] = make_uint4(u[4],u[5],u[6],u[7]);
}

// ---------- init: rbuf[0] (x_0 appended); flag slots: 0 for WGs, ~0 for unused ----------
__global__ void k_init(const float* __restrict__ x, ushort* __restrict__ r0,
                       unsigned* __restrict__ bar){
  int i = blockIdx.x*blockDim.x + threadIdx.x;
  int nthr = gridDim.x*blockDim.x;
  for (int e=i; e<256; e+=nthr) bar[e] = (e < NWG) ? 0u : 0xFFFFFFFFu;
  for (int e=i; e<BATCH*KP; e+=nthr){
    int b = e / KP, k = e % KP;
    float v = (k<NTOT) ? (is_dend(k)?0.5f:0.f) : x[b*NIN + (k-NTOT)];
    r0[e] = f2h(v);
  }
}

// ---------- persistent kernel (R19 + flat store/poll barrier) ----------
// 241 WGs x 512 thr (8 waves, 2/SIMD). WG<240: 16 cols; wave (bh,kw) = batch-half x K/4.
// Barrier: leader stores epoch to OWN slot (no RMW); wave 0 polls ALL 241 slots with
// 4 parallel 64-lane loads + __all — no counters, no release relay, one L3 round trip.
__global__ __launch_bounds__(512,1) void k_run(
    const ushort* __restrict__ WTu, ushort* rbase,
    const float* __restrict__ noise, const float* __restrict__ x,
    const float* __restrict__ bvec, const float* __restrict__ d2s,
    const float* __restrict__ w_out, const float* __restrict__ b_out,
    float* __restrict__ out, unsigned* bar)
{
  __shared__ ushort Blds[63488];           // 126,976 B: 496 kc-chunks x 16 cols x 16B
  __shared__ f32x4 red[4][2][64];          // 8 KB
  const f16* WT = (const f16*)WTu;
  const int bid = blockIdx.x;
  const int tid = threadIdx.x;
  const int wv = tid>>6, l = tid&63, l15 = l&15, lh = l>>4;
  const int bh = wv&1, kw = wv>>1;
  const int n0 = bid*16;
  const int n  = n0 + l15;                 // this lane's update col
  const int br = bh*16 + lh*4 + kw;        // this lane's update batch row
  const float NS = 0.0063245553203367585f; // sqrt(2*0.2)*0.01

  // persistent per-lane state: 1 (row, col) cell
  float hr = 0.f, im = 0.f;
  float bv=0.f, dA=0.f, dB=0.f, al=0.f;
  bool cSR=false, cPFC=false, cME=false, dendF=false;
  if (bid < 240){
    bv = bvec[n];
    cSR  = (n0 < 512);
    cPFC = (n0 >= 1920 && n0 < 2432);
    cME  = (n0 >= 2432 && n0 < 3456);
    dendF = (n0>=512 && n0<1536) || cME;
    if (cSR){  dA=d2s[n];       dB=d2s[512+n]; }
    if (cPFC){ const int j=n-1920; dA=d2s[1024+j]; dB=d2s[1536+j]; }
    if (cME){
      const float LN10 = 2.302585092994046f;
      const float CEXP = 1.6989700043360187f/511.0f;  // (log10(5000)-2)/511
      const int j = n-2432;
      al = expf(-LN10*(1.0f + CEXP*(float)(j&511)));
    }
    // ---- prologue: stage B-slice into LDS, k-chunk-major ----
    for (int c = tid; c < 16*496; c += 512){
      const int row = c / 496;             // col 0..15
      const int kc  = c - row*496;         // k-chunk 0..495
      f16x8 v = *(const f16x8*)(WT + (size_t)(n0+row)*KP + kc*8);
      *(f16x8*)((char*)Blds + kc*256 + row*16) = v;
    }
  }

  // WG 240: preload w_out columns into registers (lane l covers rows l*8..l*8+7)
  float wo[3][8];
  float bo0=0.f, bo1=0.f, bo2=0.f;
  if (bid == 240){
    #pragma unroll
    for (int o=0;o<3;o++)
      #pragma unroll
      for (int i=0;i<8;i++) wo[o][i] = w_out[(l*8+i)*3 + o];
    bo0 = b_out[0]; bo1 = b_out[1]; bo2 = b_out[2];
  }
  __syncthreads();

  // per-wave invariant LDS base for B (k-chunk-major): chunk = kw*124 + ks*4 + lh
  const char* bb = (const char*)Blds + (kw*124 + lh)*256 + l15*16;

  for (int t=0; t<TSTEPS; t++){
    const ushort* rcu = rbase + (size_t)t*RSTRIDE;       // read: buffer t (fresh addrs)
    ushort*       rnu = rbase + (size_t)(t+1)*RSTRIDE;   // write: buffer t+1
    const f16* rc = (const f16*)rcu;

    if (bid < 240){
      // ---- prefetch update operands for this lane's (row, col) cell ----
      const float nz = noise[(size_t)t*BATCH*NTOT + br*NTOT + n];
      float cA = 0.f, cB = 0.f;
      if (cSR){
        cA = h2f(rcu[br*KP + 512 +n]); cB = h2f(rcu[br*KP + 1024+n]);
      } else if (cPFC){
        const int j = n-1920;
        cA = h2f(rcu[br*KP + 2432+j]); cB = h2f(rcu[br*KP + 2944+j]);
      }

      // ---- MFMA: 16 cols x 16 batch rows x K/4 per wave; B from LDS ----
      f32x4 acc; acc.x=0.f; acc.y=0.f; acc.z=0.f; acc.w=0.f;
      {
        const f16* pa = rc + (size_t)(bh*16+l15)*KP + kw*992 + lh*8;
        #pragma unroll
        for (int ks=0; ks<31; ks++){
          f16x8 a = *(const f16x8*)(pa + ks*32);
          f16x8 b = *(const f16x8*)(bb + ks*1024);
          acc = __builtin_amdgcn_mfma_f32_16x16x32_f16(a, b, acc, 0,0,0);
        }
      }
      red[kw][bh][l] = acc;
      __syncthreads();

      // ---- all-wave fused update: wave kw owns component rg==kw ----
      {
        float p = bv;
        #pragma unroll
        for (int w=0;w<4;w++){
          f32x4 v = red[w][bh][l];
          p += (kw==0) ? v.x : (kw==1) ? v.y : (kw==2) ? v.z : v.w;
        }
        p += cA*dA + cB*dB;                       // zero for non-coupled cols
        if (cME){
          im = (1.f-al)*im + al*fmaxf(p,0.f); p += im;
        }
        hr = 0.8f*hr + 0.2f*p + NS*nz;
        const float rv = dendF ? (1.f/(1.f+expf(-hr))) : fmaxf(hr,0.f);
        __hip_atomic_store(&rnu[br*KP + n], f2h(rv),
                           __ATOMIC_RELAXED, __HIP_MEMORY_SCOPE_AGENT);
      }
    } else {
      // ---- WG 240: lane-parallel readout (overlaps others' matmul) ----
      // 96 (b,o) pairs over 8 waves = 12/wave; lane l covers k = l*8..l*8+7.
      #pragma unroll
      for (int q=0;q<12;q++){
        const int p = wv*12 + q;
        const int b = p/3, o = p%3;
        f16x8 rv8 = *(const f16x8*)(rc + (size_t)b*KP + l*8);
        float s = 0.f;
        #pragma unroll
        for (int i=0;i<8;i++) s += (float)rv8[i] * wo[o][i];
        #pragma unroll
        for (int off=32; off; off>>=1) s += __shfl_down(s, off);
        if (l==0){
          const float bo = (o==0)?bo0:((o==1)?bo1:bo2);
          out[t*BATCH*3 + b*3 + o] = s + bo;
        }
      }
      if (t+1 < TSTEPS && tid < 256){
        const int b = tid>>3, j = (tid&7)*16;
        const float* xs = x + (size_t)(t+1)*BATCH*NIN + b*NIN + j;
        #pragma unroll
        for (int q=0;q<4;q++){
          float4 v = *(const float4*)(xs + q*4);
          uint u0 = (uint)f2h(v.x) | ((uint)f2h(v.y)<<16);
          uint u1 = (uint)f2h(v.z) | ((uint)f2h(v.w)<<16);
          uint* dst = (uint*)&rnu[b*KP + NTOT + j + q*4];
          __hip_atomic_store(dst,   u0, __ATOMIC_RELAXED, __HIP_MEMORY_SCOPE_AGENT);
          __hip_atomic_store(dst+1, u1, __ATOMIC_RELAXED, __HIP_MEMORY_SCOPE_AGENT);
        }
      }
    }

    // ---- flat store/poll grid barrier (no RMW, no relay) ----
    if (t+1 < TSTEPS){
      __syncthreads();                       // drains vmcnt: sc1 stores at L3
      if (tid < 64){
        const unsigned ep = (unsigned)(t+1);
        if (tid == 0)
          __hip_atomic_store(&bar[bid], ep,
                             __ATOMIC_RELAXED, __HIP_MEMORY_SCOPE_AGENT);
        for (;;){
          unsigned v0 = __hip_atomic_load(bar + tid,
                             __ATOMIC_RELAXED, __HIP_MEMORY_SCOPE_AGENT);
          unsigned v1 = __hip_atomic_load(bar + tid + 64,
                             __ATOMIC_RELAXED, __HIP_MEMORY_SCOPE_AGENT);
          unsigned v2 = __hip_atomic_load(bar + tid + 128,
                             __ATOMIC_RELAXED, __HIP_MEMORY_SCOPE_AGENT);
          unsigned v3 = __hip_atomic_load(bar + tid + 192,
                             __ATOMIC_RELAXED, __HIP_MEMORY_SCOPE_AGENT);
          unsigned mn = min(min(v0,v1), min(v2,v3));
          if (__all(mn >= ep)) break;
          __builtin_amdgcn_s_sleep(1);
        }
        asm volatile("" ::: "memory");       // compiler barrier only (no L2 inv needed)
      }
      __syncthreads();
    }
  }
}

extern "C" void kernel_launch(void* const* d_in, const int* in_sizes, int n_in,
                              void* d_out, int out_size, void* d_ws, size_t ws_size,
                              hipStream_t stream) {
  const float* x     = (const float*)d_in[0];   // [100,32,128]
  const float* noise = (const float*)d_in[1];   // [100,32,3840]
  const float* w_rec = (const float*)d_in[2];   // [3840,3840]
  const float* w_in  = (const float*)d_in[3];   // [128,3840]
  const float* bvec  = (const float*)d_in[4];   // [3840]
  const float* d2s   = (const float*)d_in[5];   // [2048]
  const float* w_out = (const float*)d_in[6];   // [512,3]
  const float* b_out = (const float*)d_in[7];   // [3]
  // d_in[8] = mask: derived analytically
  float* out = (float*)d_out;                   // [100,32,3]

  char* ws = (char*)d_ws;
  ushort*   WT    = (ushort*)(ws);              // 30,474,240 B
  ushort*   rbase = (ushort*)(ws + 30474240);   // 101 x 253,952 B = 25,649,152 B
  unsigned* bar   = (unsigned*)(ws + 56123392); //      1,024 B (256 flag slots)

  k_prep_w<<<3720,256,0,stream>>>(w_rec, w_in, WT);
  k_init<<<64,256,0,stream>>>(x, rbase, bar);
  k_run<<<NWG,512,0,stream>>>(WT, rbase, noise, x, bvec, d2s,
                              w_out, b_out, out, bar);
}

// Round 21
// 967.922 us; speedup vs baseline: 1.2508x; 1.2508x over previous
//
#include <hip/hip_runtime.h>
#include <math.h>

typedef _Float16 f16;
typedef f16 f16x8 __attribute__((ext_vector_type(8)));
typedef float f32x4 __attribute__((ext_vector_type(4)));

#define NTOT 3840
#define KP   3968          // 3840 neurons + 128 inputs
#define BATCH 32
#define TSTEPS 100
#define NIN 128
#define NWG 241            // 240 col-tile WGs (16 cols, 512 thr) + 1 readout WG
#define RSTRIDE (BATCH*KP) // ushorts per r buffer (126,976)

__device__ __forceinline__ bool is_dend(int k){
  return (k>=512 && k<1536) || (k>=2432 && k<3456);
}
__device__ __forceinline__ bool is_inh(int k){
  return (k>=1536 && k<1920) || (k>=3456 && k<3840);
}
__device__ __forceinline__ ushort f2h(float v){ f16 h=(f16)v; return *(ushort*)&h; }
__device__ __forceinline__ float h2f(ushort u){ f16 h=*(f16*)&u; return (float)h; }

// ---------- one-time: WT[n][k] = fp16(w_eff^T), mask derived analytically ----------
__global__ __launch_bounds__(256) void k_prep_w(const float* __restrict__ w_rec,
    const float* __restrict__ w_in, ushort* __restrict__ WT){
  __shared__ ushort tile[64][72];
  const int bid = blockIdx.x;
  const int kt = bid / 60, nt = bid % 60;
  const int k0 = kt*64, n0 = nt*64;
  const int t = threadIdx.x;
  const int tr = t>>2, tq = t&3;
  const int k = k0 + tr;
  const int cbase = n0 + tq*16;
  if (k < NTOT){
    const float sgn = is_inh(k) ? -1.f : 1.f;
    const bool rowSr  = (k>=512  && k<1536);
    const bool rowPfc = (k>=2432 && k<3456);
    #pragma unroll
    for (int q=0;q<4;q++){
      float4 w = *(const float4*)(w_rec + (size_t)k*NTOT + cbase + q*4);
      float v[4] = {sgn*fabsf(w.x), sgn*fabsf(w.y), sgn*fabsf(w.z), sgn*fabsf(w.w)};
      #pragma unroll
      for (int e=0;e<4;e++){
        const int n = cbase + q*4 + e;
        if (n==k || (rowSr && n<512) || (rowPfc && n>=1920 && n<2432)) v[e]=0.f;
        tile[tr][tq*16+q*4+e] = f2h(v[e]);
      }
    }
  } else {
    const float* src = w_in + (size_t)(k-NTOT)*NTOT + cbase;
    #pragma unroll
    for (int q=0;q<4;q++){
      float4 w = *(const float4*)(src + q*4);
      tile[tr][tq*16+q*4+0] = f2h(w.x);
      tile[tr][tq*16+q*4+1] = f2h(w.y);
      tile[tr][tq*16+q*4+2] = f2h(w.z);
      tile[tr][tq*16+q*4+3] = f2h(w.w);
    }
  }
  __syncthreads();
  const int n  = n0 + tr;
  const int kq = tq*16;
  uint u[8];
  #pragma unroll
  for (int q=0;q<8;q++)
    u[q] = (uint)tile[kq+2*q][tr] | ((uint)tile[kq+2*q+1][tr] << 16);
  uint4* dst = (uint4*)(WT + (size_t)n*KP + k0 + kq);
  dst[0] = make_uint4(u[0],u[1],u[2],u[3]);
  dst[1] = make_uint4(u[4],u[5],u[6],u[7]);
}

// ---------- init: rbuf[0] (x_0 appended), barrier area zeroed ----------
__global__ void k_init(const float* __restrict__ x, ushort* __restrict__ r0,
                       unsigned* __restrict__ bar){
  int i = blockIdx.x*blockDim.x + threadIdx.x;
  int nthr = gridDim.x*blockDim.x;
  for (int e=i; e<1024; e+=nthr) bar[e] = 0u;
  for (int e=i; e<BATCH*KP; e+=nthr){
    int b = e / KP, k = e % KP;
    float v = (k<NTOT) ? (is_dend(k)?0.5f:0.f) : x[b*NIN + (k-NTOT)];
    r0[e] = f2h(v);
  }
}

// ---------- persistent kernel (R16 + all-wave update): 512 thr, B in LDS kc-major ----------
// 241 WGs x 512 thr (8 waves, 2/SIMD). WG<240: 16 cols; wave (bh,kw) = batch-half x K/4.
// ALL waves write red; after sync, wave kw owns fragment component rg==kw:
// update runs on all 8 waves (1 row x 1 col per lane), 4x the R16 parallelism.
__global__ __launch_bounds__(512,1) void k_run(
    const ushort* __restrict__ WTu, ushort* rbase,
    const float* __restrict__ noise, const float* __restrict__ x,
    const float* __restrict__ bvec, const float* __restrict__ d2s,
    const float* __restrict__ w_out, const float* __restrict__ b_out,
    float* __restrict__ out, unsigned* bar)
{
  __shared__ ushort Blds[63488];           // 126,976 B: 496 kc-chunks x 16 cols x 16B
  __shared__ f32x4 red[4][2][64];          // 8 KB
  const f16* WT = (const f16*)WTu;
  const int bid = blockIdx.x;
  const int tid = threadIdx.x;
  const int wv = tid>>6, l = tid&63, l15 = l&15, lh = l>>4;
  const int bh = wv&1, kw = wv>>1;
  const int n0 = bid*16;
  const int n  = n0 + l15;                 // this lane's update col
  const int br = bh*16 + lh*4 + kw;        // this lane's update batch row
  const float NS = 0.0063245553203367585f; // sqrt(2*0.2)*0.01

  // persistent per-lane state: 1 (row, col) cell
  float hr = 0.f, im = 0.f;
  float bv=0.f, dA=0.f, dB=0.f, al=0.f;
  bool cSR=false, cPFC=false, cME=false, dendF=false;
  if (bid < 240){
    bv = bvec[n];
    cSR  = (n0 < 512);
    cPFC = (n0 >= 1920 && n0 < 2432);
    cME  = (n0 >= 2432 && n0 < 3456);
    dendF = (n0>=512 && n0<1536) || cME;
    if (cSR){  dA=d2s[n];       dB=d2s[512+n]; }
    if (cPFC){ const int j=n-1920; dA=d2s[1024+j]; dB=d2s[1536+j]; }
    if (cME){
      const float LN10 = 2.302585092994046f;
      const float CEXP = 1.6989700043360187f/511.0f;  // (log10(5000)-2)/511
      const int j = n-2432;
      al = expf(-LN10*(1.0f + CEXP*(float)(j&511)));
    }
    // ---- prologue: stage B-slice into LDS, k-chunk-major ----
    for (int c = tid; c < 16*496; c += 512){
      const int row = c / 496;             // col 0..15
      const int kc  = c - row*496;         // k-chunk 0..495
      f16x8 v = *(const f16x8*)(WT + (size_t)(n0+row)*KP + kc*8);
      *(f16x8*)((char*)Blds + kc*256 + row*16) = v;
    }
  }

  // WG 240: preload w_out columns into registers (lane l covers rows l*8..l*8+7)
  float wo[3][8];
  float bo0=0.f, bo1=0.f, bo2=0.f;
  if (bid == 240){
    #pragma unroll
    for (int o=0;o<3;o++)
      #pragma unroll
      for (int i=0;i<8;i++) wo[o][i] = w_out[(l*8+i)*3 + o];
    bo0 = b_out[0]; bo1 = b_out[1]; bo2 = b_out[2];
  }
  __syncthreads();

  // barrier bookkeeping (monotonic epochs, no resets)
  const int xg = bid & 7;                          // pseudo-XCD group
  const unsigned mycnt = (xg==0) ? 31u : 30u;      // WGs in this group
  unsigned* xcnt = bar + xg*32;                    // arrival counter (128B apart)
  unsigned* xep  = bar + 256 + xg*32;              // group epoch (release target)
  unsigned* gcnt = bar + 512;                      // global leader counter

  // per-wave invariant LDS base for B (k-chunk-major): chunk = kw*124 + ks*4 + lh
  const char* bb = (const char*)Blds + (kw*124 + lh)*256 + l15*16;

  for (int t=0; t<TSTEPS; t++){
    const ushort* rcu = rbase + (size_t)t*RSTRIDE;       // read: buffer t (fresh addrs)
    ushort*       rnu = rbase + (size_t)(t+1)*RSTRIDE;   // write: buffer t+1
    const f16* rc = (const f16*)rcu;

    if (bid < 240){
      // ---- prefetch update operands for this lane's (row, col) cell ----
      const float nz = noise[(size_t)t*BATCH*NTOT + br*NTOT + n];
      float cA = 0.f, cB = 0.f;
      if (cSR){
        cA = h2f(rcu[br*KP + 512 +n]); cB = h2f(rcu[br*KP + 1024+n]);
      } else if (cPFC){
        const int j = n-1920;
        cA = h2f(rcu[br*KP + 2432+j]); cB = h2f(rcu[br*KP + 2944+j]);
      }

      // ---- MFMA: 16 cols x 16 batch rows x K/4 per wave; B from LDS ----
      f32x4 acc; acc.x=0.f; acc.y=0.f; acc.z=0.f; acc.w=0.f;
      {
        const f16* pa = rc + (size_t)(bh*16+l15)*KP + kw*992 + lh*8;
        #pragma unroll
        for (int ks=0; ks<31; ks++){
          f16x8 a = *(const f16x8*)(pa + ks*32);
          f16x8 b = *(const f16x8*)(bb + ks*1024);
          acc = __builtin_amdgcn_mfma_f32_16x16x32_f16(a, b, acc, 0,0,0);
        }
      }
      red[kw][bh][l] = acc;
      __syncthreads();

      // ---- all-wave fused update: wave kw owns component rg==kw ----
      {
        float p = bv;
        #pragma unroll
        for (int w=0;w<4;w++){
          f32x4 v = red[w][bh][l];
          p += (kw==0) ? v.x : (kw==1) ? v.y : (kw==2) ? v.z : v.w;
        }
        p += cA*dA + cB*dB;                       // zero for non-coupled cols
        if (cME){
          im = (1.f-al)*im + al*fmaxf(p,0.f); p += im;
        }
        hr = 0.8f*hr + 0.2f*p + NS*nz;
        const float rv = dendF ? (1.f/(1.f+expf(-hr))) : fmaxf(hr,0.f);
        __hip_atomic_store(&rnu[br*KP + n], f2h(rv),
                           __ATOMIC_RELAXED, __HIP_MEMORY_SCOPE_AGENT);
      }
    } else {
      // ---- WG 240: lane-parallel readout (overlaps others' matmul) ----
      // 96 (b,o) pairs over 8 waves = 12/wave; lane l covers k = l*8..l*8+7.
      #pragma unroll
      for (int q=0;q<12;q++){
        const int p = wv*12 + q;
        const int b = p/3, o = p%3;
        f16x8 rv8 = *(const f16x8*)(rc + (size_t)b*KP + l*8);
        float s = 0.f;
        #pragma unroll
        for (int i=0;i<8;i++) s += (float)rv8[i] * wo[o][i];
        #pragma unroll
        for (int off=32; off; off>>=1) s += __shfl_down(s, off);
        if (l==0){
          const float bo = (o==0)?bo0:((o==1)?bo1:bo2);
          out[t*BATCH*3 + b*3 + o] = s + bo;
        }
      }
      if (t+1 < TSTEPS && tid < 256){
        const int b = tid>>3, j = (tid&7)*16;
        const float* xs = x + (size_t)(t+1)*BATCH*NIN + b*NIN + j;
        #pragma unroll
        for (int q=0;q<4;q++){
          float4 v = *(const float4*)(xs + q*4);
          uint u0 = (uint)f2h(v.x) | ((uint)f2h(v.y)<<16);
          uint u1 = (uint)f2h(v.z) | ((uint)f2h(v.w)<<16);
          uint* dst = (uint*)&rnu[b*KP + NTOT + j + q*4];
          __hip_atomic_store(dst,   u0, __ATOMIC_RELAXED, __HIP_MEMORY_SCOPE_AGENT);
          __hip_atomic_store(dst+1, u1, __ATOMIC_RELAXED, __HIP_MEMORY_SCOPE_AGENT);
        }
      }
    }

    // ---- hierarchical fence-free barrier, single-hop release ----
    if (t+1 < TSTEPS){
      __syncthreads();                       // drains vmcnt: sc1 stores at L3
      if (tid == 0){
        unsigned old = __hip_atomic_fetch_add(xcnt, 1u,
                          __ATOMIC_RELAXED, __HIP_MEMORY_SCOPE_AGENT);
        if (old == mycnt*(unsigned)(t+1) - 1u){
          unsigned g = __hip_atomic_fetch_add(gcnt, 1u,
                          __ATOMIC_RELAXED, __HIP_MEMORY_SCOPE_AGENT);
          if (g == 8u*(unsigned)(t+1) - 1u){
            // last arriver releases ALL groups directly (single hop)
            #pragma unroll
            for (int grp=0; grp<8; grp++)
              __hip_atomic_store(bar + 256 + grp*32, (unsigned)(t+1),
                            __ATOMIC_RELAXED, __HIP_MEMORY_SCOPE_AGENT);
          }
        }
        while (__hip_atomic_load(xep, __ATOMIC_RELAXED,
                      __HIP_MEMORY_SCOPE_AGENT) < (unsigned)(t+1))
          __builtin_amdgcn_s_sleep(1);
        asm volatile("" ::: "memory");       // compiler barrier only (no L2 inv needed)
      }
      __syncthreads();
    }
  }
}

extern "C" void kernel_launch(void* const* d_in, const int* in_sizes, int n_in,
                              void* d_out, int out_size, void* d_ws, size_t ws_size,
                              hipStream_t stream) {
  const float* x     = (const float*)d_in[0];   // [100,32,128]
  const float* noise = (const float*)d_in[1];   // [100,32,3840]
  const float* w_rec = (const float*)d_in[2];   // [3840,3840]
  const float* w_in  = (const float*)d_in[3];   // [128,3840]
  const float* bvec  = (const float*)d_in[4];   // [3840]
  const float* d2s   = (const float*)d_in[5];   // [2048]
  const float* w_out = (const float*)d_in[6];   // [512,3]
  const float* b_out = (const float*)d_in[7];   // [3]
  // d_in[8] = mask: derived analytically
  float* out = (float*)d_out;                   // [100,32,3]

  char* ws = (char*)d_ws;
  ushort*   WT    = (ushort*)(ws);              // 30,474,240 B
  ushort*   rbase = (ushort*)(ws + 30474240);   // 101 x 253,952 B = 25,649,152 B
  unsigned* bar   = (unsigned*)(ws + 56123392); //      4,096 B

  k_prep_w<<<3720,256,0,stream>>>(w_rec, w_in, WT);
  k_init<<<64,256,0,stream>>>(x, rbase, bar);
  k_run<<<NWG,512,0,stream>>>(WT, rbase, noise, x, bvec, d2s,
                              w_out, b_out, out, bar);
}

// Round 23
// 959.829 us; speedup vs baseline: 1.2613x; 1.0084x over previous
//
#include <hip/hip_runtime.h>
#include <math.h>

typedef _Float16 f16;
typedef f16 f16x8 __attribute__((ext_vector_type(8)));
typedef float f32x4 __attribute__((ext_vector_type(4)));

#define NTOT 3840
#define KP   3968          // 3840 neurons + 128 inputs
#define BATCH 32
#define TSTEPS 100
#define NIN 128
#define NWG 241            // 240 col-tile WGs (16 cols, 512 thr) + 1 readout WG
#define RSTRIDE (BATCH*KP) // ushorts per r buffer (126,976)

__device__ __forceinline__ bool is_dend(int k){
  return (k>=512 && k<1536) || (k>=2432 && k<3456);
}
__device__ __forceinline__ bool is_inh(int k){
  return (k>=1536 && k<1920) || (k>=3456 && k<3840);
}
__device__ __forceinline__ ushort f2h(float v){ f16 h=(f16)v; return *(ushort*)&h; }
__device__ __forceinline__ float h2f(ushort u){ f16 h=*(f16*)&u; return (float)h; }

// ---------- one-time: WT[n][k] = fp16(w_eff^T), mask derived analytically ----------
__global__ __launch_bounds__(256) void k_prep_w(const float* __restrict__ w_rec,
    const float* __restrict__ w_in, ushort* __restrict__ WT){
  __shared__ ushort tile[64][72];
  const int bid = blockIdx.x;
  const int kt = bid / 60, nt = bid % 60;
  const int k0 = kt*64, n0 = nt*64;
  const int t = threadIdx.x;
  const int tr = t>>2, tq = t&3;
  const int k = k0 + tr;
  const int cbase = n0 + tq*16;
  if (k < NTOT){
    const float sgn = is_inh(k) ? -1.f : 1.f;
    const bool rowSr  = (k>=512  && k<1536);
    const bool rowPfc = (k>=2432 && k<3456);
    #pragma unroll
    for (int q=0;q<4;q++){
      float4 w = *(const float4*)(w_rec + (size_t)k*NTOT + cbase + q*4);
      float v[4] = {sgn*fabsf(w.x), sgn*fabsf(w.y), sgn*fabsf(w.z), sgn*fabsf(w.w)};
      #pragma unroll
      for (int e=0;e<4;e++){
        const int n = cbase + q*4 + e;
        if (n==k || (rowSr && n<512) || (rowPfc && n>=1920 && n<2432)) v[e]=0.f;
        tile[tr][tq*16+q*4+e] = f2h(v[e]);
      }
    }
  } else {
    const float* src = w_in + (size_t)(k-NTOT)*NTOT + cbase;
    #pragma unroll
    for (int q=0;q<4;q++){
      float4 w = *(const float4*)(src + q*4);
      tile[tr][tq*16+q*4+0] = f2h(w.x);
      tile[tr][tq*16+q*4+1] = f2h(w.y);
      tile[tr][tq*16+q*4+2] = f2h(w.z);
      tile[tr][tq*16+q*4+3] = f2h(w.w);
    }
  }
  __syncthreads();
  const int n  = n0 + tr;
  const int kq = tq*16;
  uint u[8];
  #pragma unroll
  for (int q=0;q<8;q++)
    u[q] = (uint)tile[kq+2*q][tr] | ((uint)tile[kq+2*q+1][tr] << 16);
  uint4* dst = (uint4*)(WT + (size_t)n*KP + k0 + kq);
  dst[0] = make_uint4(u[0],u[1],u[2],u[3]);
  dst[1] = make_uint4(u[4],u[5],u[6],u[7]);
}

// ---------- init: rbuf[0] (x_0 appended), barrier area zeroed ----------
__global__ void k_init(const float* __restrict__ x, ushort* __restrict__ r0,
                       unsigned* __restrict__ bar){
  int i = blockIdx.x*blockDim.x + threadIdx.x;
  int nthr = gridDim.x*blockDim.x;
  for (int e=i; e<1024; e+=nthr) bar[e] = 0u;
  for (int e=i; e<BATCH*KP; e+=nthr){
    int b = e / KP, k = e % KP;
    float v = (k<NTOT) ? (is_dend(k)?0.5f:0.f) : x[b*NIN + (k-NTOT)];
    r0[e] = f2h(v);
  }
}

// ---------- persistent kernel (R16 + all-wave update): 512 thr, B in LDS kc-major ----------
// 241 WGs x 512 thr (8 waves, 2/SIMD). WG<240: 16 cols; wave (bh,kw) = batch-half x K/4.
// ALL waves write red; after sync, wave kw owns fragment component rg==kw:
// update runs on all 8 waves (1 row x 1 col per lane), 4x the R16 parallelism.
__global__ __launch_bounds__(512,1) void k_run(
    const ushort* __restrict__ WTu, ushort* rbase,
    const float* __restrict__ noise, const float* __restrict__ x,
    const float* __restrict__ bvec, const float* __restrict__ d2s,
    const float* __restrict__ w_out, const float* __restrict__ b_out,
    float* __restrict__ out, unsigned* bar)
{
  __shared__ ushort Blds[63488];           // 126,976 B: 496 kc-chunks x 16 cols x 16B
  __shared__ f32x4 red[4][2][64];          // 8 KB
  const f16* WT = (const f16*)WTu;
  const int bid = blockIdx.x;
  const int tid = threadIdx.x;
  const int wv = tid>>6, l = tid&63, l15 = l&15, lh = l>>4;
  const int bh = wv&1, kw = wv>>1;
  const int n0 = bid*16;
  const int n  = n0 + l15;                 // this lane's update col
  const int br = bh*16 + lh*4 + kw;        // this lane's update batch row
  const float NS = 0.0063245553203367585f; // sqrt(2*0.2)*0.01

  // persistent per-lane state: 1 (row, col) cell
  float hr = 0.f, im = 0.f;
  float bv=0.f, dA=0.f, dB=0.f, al=0.f;
  bool cSR=false, cPFC=false, cME=false, dendF=false;
  if (bid < 240){
    bv = bvec[n];
    cSR  = (n0 < 512);
    cPFC = (n0 >= 1920 && n0 < 2432);
    cME  = (n0 >= 2432 && n0 < 3456);
    dendF = (n0>=512 && n0<1536) || cME;
    if (cSR){  dA=d2s[n];       dB=d2s[512+n]; }
    if (cPFC){ const int j=n-1920; dA=d2s[1024+j]; dB=d2s[1536+j]; }
    if (cME){
      const float LN10 = 2.302585092994046f;
      const float CEXP = 1.6989700043360187f/511.0f;  // (log10(5000)-2)/511
      const int j = n-2432;
      al = expf(-LN10*(1.0f + CEXP*(float)(j&511)));
    }
    // ---- prologue: stage B-slice into LDS, k-chunk-major ----
    for (int c = tid; c < 16*496; c += 512){
      const int row = c / 496;             // col 0..15
      const int kc  = c - row*496;         // k-chunk 0..495
      f16x8 v = *(const f16x8*)(WT + (size_t)(n0+row)*KP + kc*8);
      *(f16x8*)((char*)Blds + kc*256 + row*16) = v;
    }
  }

  // WG 240: preload w_out columns into registers (lane l covers rows l*8..l*8+7)
  float wo[3][8];
  float bo0=0.f, bo1=0.f, bo2=0.f;
  if (bid == 240){
    #pragma unroll
    for (int o=0;o<3;o++)
      #pragma unroll
      for (int i=0;i<8;i++) wo[o][i] = w_out[(l*8+i)*3 + o];
    bo0 = b_out[0]; bo1 = b_out[1]; bo2 = b_out[2];
  }
  __syncthreads();

  // barrier bookkeeping (monotonic epochs, no resets)
  const int xg = bid & 7;                          // pseudo-XCD group
  const unsigned mycnt = (xg==0) ? 31u : 30u;      // WGs in this group
  unsigned* xcnt = bar + xg*32;                    // arrival counter (128B apart)
  unsigned* xep  = bar + 256 + xg*32;              // group epoch (release target)
  unsigned* gcnt = bar + 512;                      // global leader counter

  // per-wave invariant LDS base for B (k-chunk-major): chunk = kw*124 + ks*4 + lh
  const char* bb = (const char*)Blds + (kw*124 + lh)*256 + l15*16;

  for (int t=0; t<TSTEPS; t++){
    const ushort* rcu = rbase + (size_t)t*RSTRIDE;       // read: buffer t (fresh addrs)
    ushort*       rnu = rbase + (size_t)(t+1)*RSTRIDE;   // write: buffer t+1
    const f16* rc = (const f16*)rcu;

    if (bid < 240){
      // ---- prefetch update operands for this lane's (row, col) cell ----
      const float nz = noise[(size_t)t*BATCH*NTOT + br*NTOT + n];
      float cA = 0.f, cB = 0.f;
      if (cSR){
        cA = h2f(rcu[br*KP + 512 +n]); cB = h2f(rcu[br*KP + 1024+n]);
      } else if (cPFC){
        const int j = n-1920;
        cA = h2f(rcu[br*KP + 2432+j]); cB = h2f(rcu[br*KP + 2944+j]);
      }

      // ---- MFMA: 16 cols x 16 batch rows x K/4 per wave; B from LDS ----
      f32x4 acc; acc.x=0.f; acc.y=0.f; acc.z=0.f; acc.w=0.f;
      {
        const f16* pa = rc + (size_t)(bh*16+l15)*KP + kw*992 + lh*8;
        #pragma unroll
        for (int ks=0; ks<31; ks++){
          f16x8 a = *(const f16x8*)(pa + ks*32);
          f16x8 b = *(const f16x8*)(bb + ks*1024);
          acc = __builtin_amdgcn_mfma_f32_16x16x32_f16(a, b, acc, 0,0,0);
        }
      }
      red[kw][bh][l] = acc;
      __syncthreads();

      // ---- all-wave fused update: wave kw owns component rg==kw ----
      {
        float p = bv;
        #pragma unroll
        for (int w=0;w<4;w++){
          f32x4 v = red[w][bh][l];
          p += (kw==0) ? v.x : (kw==1) ? v.y : (kw==2) ? v.z : v.w;
        }
        p += cA*dA + cB*dB;                       // zero for non-coupled cols
        if (cME){
          im = (1.f-al)*im + al*fmaxf(p,0.f); p += im;
        }
        hr = 0.8f*hr + 0.2f*p + NS*nz;
        const float rv = dendF ? (1.f/(1.f+expf(-hr))) : fmaxf(hr,0.f);
        __hip_atomic_store(&rnu[br*KP + n], f2h(rv),
                           __ATOMIC_RELAXED, __HIP_MEMORY_SCOPE_AGENT);
      }
    } else {
      // ---- WG 240: lane-parallel readout (overlaps others' matmul) ----
      // 96 (b,o) pairs over 8 waves = 12/wave; lane l covers k = l*8..l*8+7.
      #pragma unroll
      for (int q=0;q<12;q++){
        const int p = wv*12 + q;
        const int b = p/3, o = p%3;
        f16x8 rv8 = *(const f16x8*)(rc + (size_t)b*KP + l*8);
        float s = 0.f;
        #pragma unroll
        for (int i=0;i<8;i++) s += (float)rv8[i] * wo[o][i];
        #pragma unroll
        for (int off=32; off; off>>=1) s += __shfl_down(s, off);
        if (l==0){
          const float bo = (o==0)?bo0:((o==1)?bo1:bo2);
          out[t*BATCH*3 + b*3 + o] = s + bo;
        }
      }
      if (t+1 < TSTEPS && tid < 256){
        const int b = tid>>3, j = (tid&7)*16;
        const float* xs = x + (size_t)(t+1)*BATCH*NIN + b*NIN + j;
        #pragma unroll
        for (int q=0;q<4;q++){
          float4 v = *(const float4*)(xs + q*4);
          uint u0 = (uint)f2h(v.x) | ((uint)f2h(v.y)<<16);
          uint u1 = (uint)f2h(v.z) | ((uint)f2h(v.w)<<16);
          uint* dst = (uint*)&rnu[b*KP + NTOT + j + q*4];
          __hip_atomic_store(dst,   u0, __ATOMIC_RELAXED, __HIP_MEMORY_SCOPE_AGENT);
          __hip_atomic_store(dst+1, u1, __ATOMIC_RELAXED, __HIP_MEMORY_SCOPE_AGENT);
        }
      }
    }

    // ---- hierarchical fence-free barrier, single-hop release ----
    if (t+1 < TSTEPS){
      __syncthreads();                       // drains vmcnt: sc1 stores at L3
      if (tid == 0){
        unsigned old = __hip_atomic_fetch_add(xcnt, 1u,
                          __ATOMIC_RELAXED, __HIP_MEMORY_SCOPE_AGENT);
        if (old == mycnt*(unsigned)(t+1) - 1u){
          unsigned g = __hip_atomic_fetch_add(gcnt, 1u,
                          __ATOMIC_RELAXED, __HIP_MEMORY_SCOPE_AGENT);
          if (g == 8u*(unsigned)(t+1) - 1u){
            // last arriver releases ALL groups directly (single hop)
            #pragma unroll
            for (int grp=0; grp<8; grp++)
              __hip_atomic_store(bar + 256 + grp*32, (unsigned)(t+1),
                            __ATOMIC_RELAXED, __HIP_MEMORY_SCOPE_AGENT);
          }
        }
        while (__hip_atomic_load(xep, __ATOMIC_RELAXED,
                      __HIP_MEMORY_SCOPE_AGENT) < (unsigned)(t+1))
          __builtin_amdgcn_s_sleep(1);
        asm volatile("" ::: "memory");       // compiler barrier only (no L2 inv needed)
      }
      __syncthreads();
    }
  }
}

extern "C" void kernel_launch(void* const* d_in, const int* in_sizes, int n_in,
                              void* d_out, int out_size, void* d_ws, size_t ws_size,
                              hipStream_t stream) {
  const float* x     = (const float*)d_in[0];   // [100,32,128]
  const float* noise = (const float*)d_in[1];   // [100,32,3840]
  const float* w_rec = (const float*)d_in[2];   // [3840,3840]
  const float* w_in  = (const float*)d_in[3];   // [128,3840]
  const float* bvec  = (const float*)d_in[4];   // [3840]
  const float* d2s   = (const float*)d_in[5];   // [2048]
  const float* w_out = (const float*)d_in[6];   // [512,3]
  const float* b_out = (const float*)d_in[7];   // [3]
  // d_in[8] = mask: derived analytically
  float* out = (float*)d_out;                   // [100,32,3]

  char* ws = (char*)d_ws;
  ushort*   WT    = (ushort*)(ws);              // 30,474,240 B
  ushort*   rbase = (ushort*)(ws + 30474240);   // 101 x 253,952 B = 25,649,152 B
  unsigned* bar   = (unsigned*)(ws + 56123392); //      4,096 B

  k_prep_w<<<3720,256,0,stream>>>(w_rec, w_in, WT);
  k_init<<<64,256,0,stream>>>(x, rbase, bar);
  k_run<<<NWG,512,0,stream>>>(WT, rbase, noise, x, bvec, d2s,
                              w_out, b_out, out, bar);
}